// Round 1
// baseline (392.129 us; speedup 1.0000x reference)
//
#include <hip/hip_runtime.h>

#define BATCH 2
#define TSEQ  4096
#define CDIM  1024
#define DDIM  64
#define QB    16
#define KBLK  128
#define KTS   132   // kT row stride in floats: (4d + r) % 32 spreads banks; b64 reads dense
#define XSS   1024  // xs row stride (64KB total)

// ---------------------------------------------------------------------------
// QKV projection: rows = B*T = 8192, X[row][1024] @ W[1024][64] for q,k,v.
// 16 rows/block staged in LDS; thread (dq=tid&15, rw=tid>>4) computes row rw,
// cols 4*dq..4*dq+3 for all three matrices.
// ---------------------------------------------------------------------------
__global__ __launch_bounds__(256) void proj_qkv(
    const float* __restrict__ X,
    const float* __restrict__ Wq,
    const float* __restrict__ Wk,
    const float* __restrict__ Wv,
    float* __restrict__ Qo, float* __restrict__ Ko, float* __restrict__ Vo)
{
    __shared__ float xs[16 * XSS];
    const int tid = threadIdx.x;
    const long g0 = (long)blockIdx.x * 16;

    // stage 16 rows of X (16K floats) coalesced as float4
    #pragma unroll
    for (int it = 0; it < 16; ++it) {
        int idx = it * 256 + tid;      // float4 index 0..4095
        int row = idx >> 8;
        int c4  = idx & 255;
        float4 xv = *reinterpret_cast<const float4*>(X + (g0 + row) * CDIM + (c4 << 2));
        *reinterpret_cast<float4*>(&xs[row * XSS + (c4 << 2)]) = xv;
    }
    __syncthreads();

    const int dq = tid & 15;
    const int rw = tid >> 4;
    const float* xr = &xs[rw * XSS];
    const float4* wq4 = reinterpret_cast<const float4*>(Wq) + dq;
    const float4* wk4 = reinterpret_cast<const float4*>(Wk) + dq;
    const float4* wv4 = reinterpret_cast<const float4*>(Wv) + dq;

    float4 aq = make_float4(0.f, 0.f, 0.f, 0.f);
    float4 ak = make_float4(0.f, 0.f, 0.f, 0.f);
    float4 av = make_float4(0.f, 0.f, 0.f, 0.f);

    for (int c0 = 0; c0 < CDIM; c0 += 4) {
        float4 xv4 = *reinterpret_cast<const float4*>(xr + c0);
        #pragma unroll
        for (int u = 0; u < 4; ++u) {
            float xv = (u == 0) ? xv4.x : (u == 1) ? xv4.y : (u == 2) ? xv4.z : xv4.w;
            float4 wq = wq4[(c0 + u) * 16];
            float4 wk = wk4[(c0 + u) * 16];
            float4 wv = wv4[(c0 + u) * 16];
            aq.x = fmaf(xv, wq.x, aq.x); aq.y = fmaf(xv, wq.y, aq.y);
            aq.z = fmaf(xv, wq.z, aq.z); aq.w = fmaf(xv, wq.w, aq.w);
            ak.x = fmaf(xv, wk.x, ak.x); ak.y = fmaf(xv, wk.y, ak.y);
            ak.z = fmaf(xv, wk.z, ak.z); ak.w = fmaf(xv, wk.w, ak.w);
            av.x = fmaf(xv, wv.x, av.x); av.y = fmaf(xv, wv.y, av.y);
            av.z = fmaf(xv, wv.z, av.z); av.w = fmaf(xv, wv.w, av.w);
        }
    }

    const long orow = g0 + rw;
    *reinterpret_cast<float4*>(Qo + orow * DDIM + (dq << 2)) = aq;
    *reinterpret_cast<float4*>(Ko + orow * DDIM + (dq << 2)) = ak;
    *reinterpret_cast<float4*>(Vo + orow * DDIM + (dq << 2)) = av;
}

// ---------------------------------------------------------------------------
// Causal flash attention, fp32. Block = 16 query rows (4 rows per wave, online
// softmax state in registers per wave). K chunk (128 rows) staged transposed
// in LDS; V read straight from global (L1/L2 resident), PV accumulated as
// per-lane partials over the jq = lane>>4 key subset, reduced at the end.
// ---------------------------------------------------------------------------
__global__ __launch_bounds__(256) void attn_fused(
    const float* __restrict__ Q, const float* __restrict__ K,
    const float* __restrict__ V, float* __restrict__ O)
{
    __shared__ float kT[DDIM * KTS];     // kT[d][r] = K[kb+r][d]
    __shared__ float ps[16 * KBLK];      // [wave*4+ri][j]
    __shared__ float qsT[DDIM * 16];     // qsT[d][r] = Q[r0+r][d]

    const int tid  = threadIdx.x;
    const int lane = tid & 63;
    const int wave = tid >> 6;
    const int b    = blockIdx.y;
    const int qb   = (int)gridDim.x - 1 - (int)blockIdx.x;  // heavy blocks first
    const long bb  = (long)b * TSEQ;
    const int r0   = qb * QB;

    // stage q tile transposed (one-time; conflicts here are negligible)
    #pragma unroll
    for (int it = 0; it < 4; ++it) {
        int idx = it * 256 + tid;
        int d = idx & 63, r = idx >> 6;
        qsT[d * 16 + r] = Q[(bb + r0 + r) * DDIM + d];
    }

    float m[4], l[4], acc[4][4];
    #pragma unroll
    for (int i = 0; i < 4; ++i) {
        m[i] = -1e30f; l[i] = 0.f;
        acc[i][0] = 0.f; acc[i][1] = 0.f; acc[i][2] = 0.f; acc[i][3] = 0.f;
    }

    const int dq = lane & 15;   // also used as row-part in staging
    const int jq = lane >> 4;
    const int nch = (r0 + QB + KBLK - 1) / KBLK;

    for (int ch = 0; ch < nch; ++ch) {
        const int kb = ch * KBLK;
        __syncthreads();   // waves done reading kT of previous chunk (covers qsT too on ch=0)

        // stage K chunk transposed: kT[d][r], writes 2-way bank-free via KTS=132
        #pragma unroll
        for (int rr = 0; rr < 2; ++rr) {
            #pragma unroll
            for (int ii = 0; ii < 4; ++ii) {
                int r  = rr * 64 + wave * 16 + dq;
                int d0 = ii * 16 + (jq << 2);
                float4 kv = *reinterpret_cast<const float4*>(K + (bb + kb + r) * DDIM + d0);
                kT[(d0 + 0) * KTS + r] = kv.x;
                kT[(d0 + 1) * KTS + r] = kv.y;
                kT[(d0 + 2) * KTS + r] = kv.z;
                kT[(d0 + 3) * KTS + r] = kv.w;
            }
        }
        __syncthreads();

        // scores: rows wave*4+ri, keys j = 2*lane+ji
        float s00 = 0.f, s01 = 0.f, s10 = 0.f, s11 = 0.f;
        float s20 = 0.f, s21 = 0.f, s30 = 0.f, s31 = 0.f;
        #pragma unroll 4
        for (int d = 0; d < DDIM; ++d) {
            float4 qv = *reinterpret_cast<const float4*>(&qsT[d * 16 + (wave << 2)]);
            float2 kv = *reinterpret_cast<const float2*>(&kT[d * KTS + (lane << 1)]);
            s00 = fmaf(qv.x, kv.x, s00); s01 = fmaf(qv.x, kv.y, s01);
            s10 = fmaf(qv.y, kv.x, s10); s11 = fmaf(qv.y, kv.y, s11);
            s20 = fmaf(qv.z, kv.x, s20); s21 = fmaf(qv.z, kv.y, s21);
            s30 = fmaf(qv.w, kv.x, s30); s31 = fmaf(qv.w, kv.y, s31);
        }
        float sr[4][2] = {{s00, s01}, {s10, s11}, {s20, s21}, {s30, s31}};

        // online softmax per row (each wave owns rows wave*4 .. wave*4+3)
        #pragma unroll
        for (int ri = 0; ri < 4; ++ri) {
            const int R  = r0 + (wave << 2) + ri;
            const int j0 = kb + (lane << 1);
            float v0 = (j0     <= R) ? sr[ri][0] * 0.125f : -1e30f;
            float v1 = (j0 + 1 <= R) ? sr[ri][1] * 0.125f : -1e30f;
            float mm = fmaxf(v0, v1);
            #pragma unroll
            for (int off = 32; off > 0; off >>= 1) mm = fmaxf(mm, __shfl_xor(mm, off));
            const float mn = fmaxf(m[ri], mm);
            const float alpha = __expf(m[ri] - mn);
            m[ri] = mn;
            const float p0 = __expf(v0 - mn);
            const float p1 = __expf(v1 - mn);
            float lsum = p0 + p1;
            #pragma unroll
            for (int off = 32; off > 0; off >>= 1) lsum += __shfl_xor(lsum, off);
            l[ri] = l[ri] * alpha + lsum;
            acc[ri][0] *= alpha; acc[ri][1] *= alpha;
            acc[ri][2] *= alpha; acc[ri][3] *= alpha;
            *reinterpret_cast<float2*>(&ps[((wave << 2) + ri) * KBLK + (lane << 1)])
                = make_float2(p0, p1);
        }

        // PV: lane (dq, jq) accumulates cols 4dq..+3 over keys j ≡ jq (mod 4)
        #pragma unroll 4
        for (int jb = 0; jb < KBLK / 4; ++jb) {
            const int j = (jb << 2) + jq;
            float4 vv = *reinterpret_cast<const float4*>(V + (bb + kb + j) * DDIM + (dq << 2));
            #pragma unroll
            for (int ri = 0; ri < 4; ++ri) {
                float p = ps[((wave << 2) + ri) * KBLK + j];
                acc[ri][0] = fmaf(p, vv.x, acc[ri][0]);
                acc[ri][1] = fmaf(p, vv.y, acc[ri][1]);
                acc[ri][2] = fmaf(p, vv.z, acc[ri][2]);
                acc[ri][3] = fmaf(p, vv.w, acc[ri][3]);
            }
        }
    }

    // reduce PV partials across the 4 jq groups (lane bits 4,5)
    #pragma unroll
    for (int ri = 0; ri < 4; ++ri) {
        #pragma unroll
        for (int c = 0; c < 4; ++c) {
            float v0 = acc[ri][c];
            v0 += __shfl_xor(v0, 16);
            v0 += __shfl_xor(v0, 32);
            acc[ri][c] = v0;
        }
    }

    // lane (dq, jq) stores row wave*4+jq, cols 4dq..+3 (static-index selects)
    const float lsel = (jq == 0) ? l[0] : (jq == 1) ? l[1] : (jq == 2) ? l[2] : l[3];
    const float invl = 1.0f / lsel;
    float4 o;
    o.x = ((jq == 0) ? acc[0][0] : (jq == 1) ? acc[1][0] : (jq == 2) ? acc[2][0] : acc[3][0]) * invl;
    o.y = ((jq == 0) ? acc[0][1] : (jq == 1) ? acc[1][1] : (jq == 2) ? acc[2][1] : acc[3][1]) * invl;
    o.z = ((jq == 0) ? acc[0][2] : (jq == 1) ? acc[1][2] : (jq == 2) ? acc[2][2] : acc[3][2]) * invl;
    o.w = ((jq == 0) ? acc[0][3] : (jq == 1) ? acc[1][3] : (jq == 2) ? acc[2][3] : acc[3][3]) * invl;
    *reinterpret_cast<float4*>(O + (bb + r0 + (wave << 2) + jq) * DDIM + (dq << 2)) = o;
}

extern "C" void kernel_launch(void* const* d_in, const int* in_sizes, int n_in,
                              void* d_out, int out_size, void* d_ws, size_t ws_size,
                              hipStream_t stream)
{
    const float* X  = (const float*)d_in[0];
    const float* Wq = (const float*)d_in[1];
    const float* Wk = (const float*)d_in[2];
    const float* Wv = (const float*)d_in[3];
    float* O = (float*)d_out;

    const size_t nrow = (size_t)BATCH * TSEQ;       // 8192
    float* Qb = (float*)d_ws;                       // 3 * 8192 * 64 floats = 6 MB
    float* Kb = Qb + nrow * DDIM;
    float* Vb = Kb + nrow * DDIM;

    proj_qkv<<<dim3(nrow / 16), 256, 0, stream>>>(X, Wq, Wk, Wv, Qb, Kb, Vb);
    attn_fused<<<dim3(TSEQ / QB, BATCH), 256, 0, stream>>>(Qb, Kb, Vb, O);
}

// Round 2
// 104.022 us; speedup vs baseline: 3.7697x; 3.7697x over previous
//
#include <hip/hip_runtime.h>

#define SEGS 4

typedef __bf16 bf16_t;
typedef __bf16 bf16x8 __attribute__((ext_vector_type(8)));
typedef __bf16 bf16x4 __attribute__((ext_vector_type(4)));
typedef float  f32x4  __attribute__((ext_vector_type(4)));

// ---------------------------------------------------------------------------
// wsplit: W[1024][64] (q,k,v fp32) -> wT_hi/wT_lo [192][1024] bf16 (transposed,
// split).  48 blocks: (mat 0..2) x (kblk 0..15, 64 rows each).
// ---------------------------------------------------------------------------
__global__ __launch_bounds__(256) void wsplit_k(
    const float* __restrict__ Wq, const float* __restrict__ Wk,
    const float* __restrict__ Wv,
    bf16_t* __restrict__ wTh, bf16_t* __restrict__ wTl)
{
    __shared__ bf16_t th[64][72];
    __shared__ bf16_t tl[64][72];
    const int mat = blockIdx.x / 16;
    const int kb  = (blockIdx.x % 16) * 64;
    const float* W = (mat == 0) ? Wq : ((mat == 1) ? Wk : Wv);
    const int t  = threadIdx.x;
    const int kl = t >> 2;          // k_local 0..63
    const int dc = (t & 3) * 16;    // d chunk base
    #pragma unroll
    for (int i = 0; i < 4; ++i) {
        float4 v = *reinterpret_cast<const float4*>(W + (long)(kb + kl) * 64 + dc + 4 * i);
        float f0 = v.x, f1 = v.y, f2 = v.z, f3 = v.w;
        bf16_t h0 = (bf16_t)f0, h1 = (bf16_t)f1, h2 = (bf16_t)f2, h3 = (bf16_t)f3;
        th[dc + 4*i + 0][kl] = h0;  tl[dc + 4*i + 0][kl] = (bf16_t)(f0 - (float)h0);
        th[dc + 4*i + 1][kl] = h1;  tl[dc + 4*i + 1][kl] = (bf16_t)(f1 - (float)h1);
        th[dc + 4*i + 2][kl] = h2;  tl[dc + 4*i + 2][kl] = (bf16_t)(f2 - (float)h2);
        th[dc + 4*i + 3][kl] = h3;  tl[dc + 4*i + 3][kl] = (bf16_t)(f3 - (float)h3);
    }
    __syncthreads();
    const int d  = t >> 2;
    const int kc = (t & 3) * 16;
    bf16x8 a0 = *reinterpret_cast<const bf16x8*>(&th[d][kc]);
    bf16x8 a1 = *reinterpret_cast<const bf16x8*>(&th[d][kc + 8]);
    bf16x8 b0 = *reinterpret_cast<const bf16x8*>(&tl[d][kc]);
    bf16x8 b1 = *reinterpret_cast<const bf16x8*>(&tl[d][kc + 8]);
    long o = (long)(mat * 64 + d) * 1024 + kb + kc;
    *reinterpret_cast<bf16x8*>(wTh + o)     = a0;
    *reinterpret_cast<bf16x8*>(wTh + o + 8) = a1;
    *reinterpret_cast<bf16x8*>(wTl + o)     = b0;
    *reinterpret_cast<bf16x8*>(wTl + o + 8) = b1;
}

// ---------------------------------------------------------------------------
// proj: C[8192][192] = X[8192][1024] @ W^T-split, 3-term bf16 MFMA split.
// 256 blocks x 32 rows; 4 waves; wave w owns N-tiles {w, w+4, w+8}
// (one 16-col tile of each of q,k,v, d-range 16w..16w+15).
// Outputs: q_hi/q_lo (pre-scaled by 0.125, exact split), k_hi, vT (transposed).
// ---------------------------------------------------------------------------
__global__ __launch_bounds__(256) void proj_mfma(
    const float* __restrict__ X,
    const bf16_t* __restrict__ wTh, const bf16_t* __restrict__ wTl,
    bf16_t* __restrict__ qh, bf16_t* __restrict__ ql,
    bf16_t* __restrict__ kh, bf16_t* __restrict__ vt)
{
    __shared__ __align__(16) bf16_t xh[32][40];
    __shared__ __align__(16) bf16_t xl[32][40];
    __shared__ float vtl[64][34];

    const int tid = threadIdx.x;
    const int lane = tid & 63;
    const int w = tid >> 6;
    const int q4 = lane & 15;
    const int g  = lane >> 4;
    const long R0 = (long)blockIdx.x * 32;

    f32x4 acc[2][3] = {};

    for (int ks = 0; ks < 32; ++ks) {
        const int k0 = ks * 32;
        {   // stage X slice [32 rows][32 k] -> bf16 hi/lo
            const int row = tid >> 3;
            const int kc  = (tid & 7) * 4;
            float4 xv = *reinterpret_cast<const float4*>(X + (R0 + row) * 1024 + k0 + kc);
            bf16_t h0 = (bf16_t)xv.x, h1 = (bf16_t)xv.y, h2 = (bf16_t)xv.z, h3 = (bf16_t)xv.w;
            bf16x4 hv = {h0, h1, h2, h3};
            bf16x4 lv = {(bf16_t)(xv.x - (float)h0), (bf16_t)(xv.y - (float)h1),
                         (bf16_t)(xv.z - (float)h2), (bf16_t)(xv.w - (float)h3)};
            *reinterpret_cast<bf16x4*>(&xh[row][kc]) = hv;
            *reinterpret_cast<bf16x4*>(&xl[row][kc]) = lv;
        }
        __syncthreads();
        bf16x8 xhf[2], xlf[2];
        #pragma unroll
        for (int mm = 0; mm < 2; ++mm) {
            xhf[mm] = *reinterpret_cast<const bf16x8*>(&xh[16 * mm + q4][8 * g]);
            xlf[mm] = *reinterpret_cast<const bf16x8*>(&xl[16 * mm + q4][8 * g]);
        }
        #pragma unroll
        for (int j = 0; j < 3; ++j) {
            const int nt = w + 4 * j;
            long wo = (long)(nt * 16 + q4) * 1024 + k0 + 8 * g;
            bf16x8 whf = *reinterpret_cast<const bf16x8*>(wTh + wo);
            bf16x8 wlf = *reinterpret_cast<const bf16x8*>(wTl + wo);
            #pragma unroll
            for (int mm = 0; mm < 2; ++mm) {
                acc[mm][j] = __builtin_amdgcn_mfma_f32_16x16x32_bf16(xhf[mm], whf, acc[mm][j], 0, 0, 0);
                acc[mm][j] = __builtin_amdgcn_mfma_f32_16x16x32_bf16(xlf[mm], whf, acc[mm][j], 0, 0, 0);
                acc[mm][j] = __builtin_amdgcn_mfma_f32_16x16x32_bf16(xhf[mm], wlf, acc[mm][j], 0, 0, 0);
            }
        }
        __syncthreads();
    }

    // epilogue: j=0 -> Q (scaled 0.125, split), j=1 -> K, j=2 -> V (LDS transpose)
    #pragma unroll
    for (int mm = 0; mm < 2; ++mm)
        #pragma unroll
        for (int r = 0; r < 4; ++r) {
            long row = R0 + 16 * mm + 4 * g + r;
            float qv = acc[mm][0][r] * 0.125f;
            bf16_t qhv = (bf16_t)qv;
            qh[row * 64 + 16 * w + q4] = qhv;
            ql[row * 64 + 16 * w + q4] = (bf16_t)(qv - (float)qhv);
            kh[row * 64 + 16 * w + q4] = (bf16_t)acc[mm][1][r];
            vtl[16 * w + q4][16 * mm + 4 * g + r] = acc[mm][2][r];
        }
    __syncthreads();
    {
        const int d  = tid >> 2;
        const int rc = (tid & 3) * 8;
        bf16x8 o;
        #pragma unroll
        for (int i = 0; i < 8; ++i) o[i] = (bf16_t)vtl[d][rc + i];
        *reinterpret_cast<bf16x8*>(vt + (long)d * 8192 + R0 + rc) = o;
    }
}

// ---------------------------------------------------------------------------
// attn: flash attention, 1 wave = 16 queries, swapped QK^T, O^T PV.
// grid (512 tiles heavy-first, SEGS key segments).  Partials (m,l,O) to ws.
// ---------------------------------------------------------------------------
__global__ __launch_bounds__(64) void attn_mfma(
    const bf16_t* __restrict__ qh, const bf16_t* __restrict__ ql,
    const bf16_t* __restrict__ kh, const bf16_t* __restrict__ vt,
    float* __restrict__ pO, float* __restrict__ pm, float* __restrict__ plv)
{
    __shared__ __align__(16) bf16_t P[2][8][16][8];   // [hilo][keyblk][q][key_in]
    __shared__ __align__(16) float ot[16][72];

    const int lane = threadIdx.x;
    const int q4 = lane & 15;
    const int g  = lane >> 4;
    const int bx = blockIdx.x;
    const int seg = blockIdx.y;
    const int qi = 255 - (bx >> 1);        // heavy tiles first
    const int b  = bx & 1;
    const int r0 = qi << 4;
    const int tile = (b << 8) + qi;        // 0..511
    const long base = (long)b * 4096;
    const int C = (r0 >> 6) + 1;           // causal chunk count (64 keys each)

    // Q B-frags (q pre-scaled by 0.125 in proj)
    const bf16_t* qrh = qh + (base + r0 + q4) * 64 + 8 * g;
    const bf16_t* qrl = ql + (base + r0 + q4) * 64 + 8 * g;
    const bf16x8 qhf0 = *reinterpret_cast<const bf16x8*>(qrh);
    const bf16x8 qhf1 = *reinterpret_cast<const bf16x8*>(qrh + 32);
    const bf16x8 qlf0 = *reinterpret_cast<const bf16x8*>(qrl);
    const bf16x8 qlf1 = *reinterpret_cast<const bf16x8*>(qrl + 32);

    float m = -1e30f, l = 0.f;
    f32x4 oacc[4] = {};   // O^T: d = 16dt + 4g + r, q = q4

    for (int c = seg; c < C; c += SEGS) {
        const int kb = c << 6;
        // ---- S^T tiles: key row = kb + 16kt + 4g + r, q col = q4
        f32x4 sacc[4];
        #pragma unroll
        for (int kt = 0; kt < 4; ++kt) {
            const bf16_t* krow = kh + (base + kb + kt * 16 + q4) * 64 + 8 * g;
            bf16x8 kf0 = *reinterpret_cast<const bf16x8*>(krow);
            bf16x8 kf1 = *reinterpret_cast<const bf16x8*>(krow + 32);
            f32x4 a = {};
            a = __builtin_amdgcn_mfma_f32_16x16x32_bf16(kf0, qhf0, a, 0, 0, 0);
            a = __builtin_amdgcn_mfma_f32_16x16x32_bf16(kf0, qlf0, a, 0, 0, 0);
            a = __builtin_amdgcn_mfma_f32_16x16x32_bf16(kf1, qhf1, a, 0, 0, 0);
            a = __builtin_amdgcn_mfma_f32_16x16x32_bf16(kf1, qlf1, a, 0, 0, 0);
            sacc[kt] = a;
        }
        // ---- online softmax (per lane: 16 scores, all for query q4)
        float p[16];
        const bool diag = (c == C - 1);
        float mx = -1e30f;
        #pragma unroll
        for (int kt = 0; kt < 4; ++kt)
            #pragma unroll
            for (int r = 0; r < 4; ++r) {
                float sv = sacc[kt][r];
                if (diag) {
                    int key = kb + kt * 16 + 4 * g + r;
                    if (key > r0 + q4) sv = -1e30f;
                }
                p[kt * 4 + r] = sv;
                mx = fmaxf(mx, sv);
            }
        mx = fmaxf(mx, __shfl_xor(mx, 16));
        mx = fmaxf(mx, __shfl_xor(mx, 32));
        const float mnew = fmaxf(m, mx);
        const float alpha = __expf(m - mnew);
        m = mnew;
        float lsum = 0.f;
        #pragma unroll
        for (int i = 0; i < 16; ++i) { p[i] = __expf(p[i] - mnew); lsum += p[i]; }
        lsum += __shfl_xor(lsum, 16);
        lsum += __shfl_xor(lsum, 32);
        l = l * alpha + lsum;
        #pragma unroll
        for (int dt = 0; dt < 4; ++dt) oacc[dt] *= alpha;
        // ---- pack P hi/lo to LDS: [cb = key>>3][q][key&7]
        #pragma unroll
        for (int kt = 0; kt < 4; ++kt) {
            const int cb = 2 * kt + (g >> 1);
            const int ki = (g & 1) << 2;
            float v0 = p[4*kt+0], v1 = p[4*kt+1], v2 = p[4*kt+2], v3 = p[4*kt+3];
            bf16_t h0 = (bf16_t)v0, h1 = (bf16_t)v1, h2 = (bf16_t)v2, h3 = (bf16_t)v3;
            bf16x4 hv = {h0, h1, h2, h3};
            bf16x4 lv = {(bf16_t)(v0 - (float)h0), (bf16_t)(v1 - (float)h1),
                         (bf16_t)(v2 - (float)h2), (bf16_t)(v3 - (float)h3)};
            *reinterpret_cast<bf16x4*>(&P[0][cb][q4][ki]) = hv;
            *reinterpret_cast<bf16x4*>(&P[1][cb][q4][ki]) = lv;
        }
        // ---- PV: O^T += V^T-tile x P^T  (single wave: compiler orders LDS)
        bf16x8 ph0 = *reinterpret_cast<const bf16x8*>(&P[0][g][q4][0]);
        bf16x8 ph1 = *reinterpret_cast<const bf16x8*>(&P[0][4 + g][q4][0]);
        bf16x8 pl0 = *reinterpret_cast<const bf16x8*>(&P[1][g][q4][0]);
        bf16x8 pl1 = *reinterpret_cast<const bf16x8*>(&P[1][4 + g][q4][0]);
        #pragma unroll
        for (int dt = 0; dt < 4; ++dt) {
            const bf16_t* vr = vt + (long)(dt * 16 + q4) * 8192 + base + kb + 8 * g;
            bf16x8 va0 = *reinterpret_cast<const bf16x8*>(vr);
            bf16x8 va1 = *reinterpret_cast<const bf16x8*>(vr + 32);
            oacc[dt] = __builtin_amdgcn_mfma_f32_16x16x32_bf16(va0, ph0, oacc[dt], 0, 0, 0);
            oacc[dt] = __builtin_amdgcn_mfma_f32_16x16x32_bf16(va0, pl0, oacc[dt], 0, 0, 0);
            oacc[dt] = __builtin_amdgcn_mfma_f32_16x16x32_bf16(va1, ph1, oacc[dt], 0, 0, 0);
            oacc[dt] = __builtin_amdgcn_mfma_f32_16x16x32_bf16(va1, pl1, oacc[dt], 0, 0, 0);
        }
    }

    // ---- epilogue: O^T -> ot[q][d] -> coalesced partial store
    #pragma unroll
    for (int dt = 0; dt < 4; ++dt)
        #pragma unroll
        for (int r = 0; r < 4; ++r)
            ot[q4][dt * 16 + 4 * g + r] = oacc[dt][r];
    const int qq  = lane >> 2;
    const int dcb = (lane & 3) << 4;
    float* dst = pO + (((long)seg * 512 + tile) * 16 + qq) * 64 + dcb;
    const float* src = &ot[qq][dcb];
    #pragma unroll
    for (int i = 0; i < 4; ++i)
        *reinterpret_cast<f32x4*>(dst + 4 * i) = *reinterpret_cast<const f32x4*>(src + 4 * i);
    if (g == 0) {
        pm[((long)seg * 512 + tile) * 16 + q4]  = m;
        plv[((long)seg * 512 + tile) * 16 + q4] = l;
    }
}

// ---------------------------------------------------------------------------
// merge: combine SEGS partials per q-tile -> final O (fp32).
// ---------------------------------------------------------------------------
__global__ __launch_bounds__(256) void merge_k(
    const float* __restrict__ pO, const float* __restrict__ pm,
    const float* __restrict__ plv, float* __restrict__ O)
{
    const int tile = blockIdx.x;
    const int t = threadIdx.x;
    const int q  = t >> 4;
    const int dc = (t & 15) << 2;
    float ms[SEGS], ls[SEGS];
    #pragma unroll
    for (int s = 0; s < SEGS; ++s) {
        ms[s] = pm[((long)s * 512 + tile) * 16 + q];
        ls[s] = plv[((long)s * 512 + tile) * 16 + q];
    }
    float mstar = ms[0];
    #pragma unroll
    for (int s = 1; s < SEGS; ++s) mstar = fmaxf(mstar, ms[s]);
    float L = 0.f;
    f32x4 o = {};
    #pragma unroll
    for (int s = 0; s < SEGS; ++s) {
        float wgt = __expf(ms[s] - mstar);
        L += wgt * ls[s];
        f32x4 po = *reinterpret_cast<const f32x4*>(pO + (((long)s * 512 + tile) * 16 + q) * 64 + dc);
        o += po * wgt;
    }
    f32x4 res = o * (1.0f / L);
    *reinterpret_cast<f32x4*>(O + ((long)tile * 16 + q) * 64 + dc) = res;
}

extern "C" void kernel_launch(void* const* d_in, const int* in_sizes, int n_in,
                              void* d_out, int out_size, void* d_ws, size_t ws_size,
                              hipStream_t stream)
{
    const float* X  = (const float*)d_in[0];
    const float* Wq = (const float*)d_in[1];
    const float* Wk = (const float*)d_in[2];
    const float* Wv = (const float*)d_in[3];
    float* O = (float*)d_out;

    char* ws = (char*)d_ws;
    size_t off = 0;
    bf16_t* wTh = (bf16_t*)(ws + off); off += 192 * 1024 * sizeof(bf16_t);   // 384 KB
    bf16_t* wTl = (bf16_t*)(ws + off); off += 192 * 1024 * sizeof(bf16_t);
    bf16_t* qh  = (bf16_t*)(ws + off); off += 8192 * 64 * sizeof(bf16_t);    // 1 MB each
    bf16_t* ql  = (bf16_t*)(ws + off); off += 8192 * 64 * sizeof(bf16_t);
    bf16_t* kh  = (bf16_t*)(ws + off); off += 8192 * 64 * sizeof(bf16_t);
    bf16_t* vt  = (bf16_t*)(ws + off); off += 64 * 8192 * sizeof(bf16_t);
    float*  pO  = (float*)(ws + off);  off += (size_t)SEGS * 512 * 16 * 64 * sizeof(float); // 8 MB
    float*  pm  = (float*)(ws + off);  off += (size_t)SEGS * 512 * 16 * sizeof(float);
    float*  plv = (float*)(ws + off);  off += (size_t)SEGS * 512 * 16 * sizeof(float);

    wsplit_k<<<48, 256, 0, stream>>>(Wq, Wk, Wv, wTh, wTl);
    proj_mfma<<<256, 256, 0, stream>>>(X, wTh, wTl, qh, ql, kh, vt);
    attn_mfma<<<dim3(512, SEGS), 64, 0, stream>>>(qh, ql, kh, vt, pO, pm, plv);
    merge_k<<<512, 256, 0, stream>>>(pO, pm, plv, O);
}

// Round 3
// 89.047 us; speedup vs baseline: 4.4036x; 1.1682x over previous
//
#include <hip/hip_runtime.h>

typedef __bf16 bf16_t;
typedef __bf16 bf16x8 __attribute__((ext_vector_type(8)));
typedef __bf16 bf16x4 __attribute__((ext_vector_type(4)));
typedef float  f32x4  __attribute__((ext_vector_type(4)));
typedef _Float16 f16_t;
typedef _Float16 f16x8 __attribute__((ext_vector_type(8)));

#define TSEQ 4096
#define SEGS 8

// ---------------------------------------------------------------------------
// wsplit: W[1024][64] (q,k,v fp32) -> wT[192][1024] bf16 (transposed).
// ---------------------------------------------------------------------------
__global__ __launch_bounds__(256) void wsplit_k(
    const float* __restrict__ Wq, const float* __restrict__ Wk,
    const float* __restrict__ Wv, bf16_t* __restrict__ wT)
{
    __shared__ bf16_t th[64][72];
    const int mat = blockIdx.x >> 4;
    const int kb  = (blockIdx.x & 15) * 64;
    const float* W = (mat == 0) ? Wq : ((mat == 1) ? Wk : Wv);
    const int t  = threadIdx.x;
    const int kl = t >> 2;
    const int dc = (t & 3) * 16;
    #pragma unroll
    for (int i = 0; i < 4; ++i) {
        float4 v = *reinterpret_cast<const float4*>(W + (long)(kb + kl) * 64 + dc + 4 * i);
        th[dc + 4*i + 0][kl] = (bf16_t)v.x;
        th[dc + 4*i + 1][kl] = (bf16_t)v.y;
        th[dc + 4*i + 2][kl] = (bf16_t)v.z;
        th[dc + 4*i + 3][kl] = (bf16_t)v.w;
    }
    __syncthreads();
    const int d  = t >> 2;
    const int kc = (t & 3) * 16;
    bf16x8 a0 = *reinterpret_cast<const bf16x8*>(&th[d][kc]);
    bf16x8 a1 = *reinterpret_cast<const bf16x8*>(&th[d][kc + 8]);
    long o = (long)(mat * 64 + d) * 1024 + kb + kc;
    *reinterpret_cast<bf16x8*>(wT + o)     = a0;
    *reinterpret_cast<bf16x8*>(wT + o + 8) = a1;
}

// ---------------------------------------------------------------------------
// proj: [8192][192] = X @ W^T, single bf16 MFMA.  256 blocks x 32 rows,
// 4 waves = Msplit2 x Nsplit2; wave = 16 rows x 6 N-tiles.  W slice (12KB)
// double-buffered in padded LDS; X loaded direct to A-frags (prefetched).
// Outputs: qh (scaled 0.125), kh, vt (transposed [64][8192]).
// ---------------------------------------------------------------------------
__global__ __launch_bounds__(256) void proj_mfma(
    const float* __restrict__ X, const bf16_t* __restrict__ wT,
    bf16_t* __restrict__ qh, bf16_t* __restrict__ kh, bf16_t* __restrict__ vt)
{
    __shared__ __align__(16) bf16_t wl[2][192][36];  // pad 36 -> <=2-way on frag read
    __shared__ float vtl[64][33];

    const int tid  = threadIdx.x;
    const int lane = tid & 63;
    const int w    = tid >> 6;
    const int mw = w >> 1, nw = w & 1;
    const int q4 = lane & 15, g = lane >> 4;
    const long R0 = (long)blockIdx.x * 32;

    f32x4 acc[6] = {};
    const float* xrow = X + (R0 + 16 * mw + q4) * 1024 + 8 * g;

    // prologue: stage W k-step 0, prefetch X k-step 0
    #pragma unroll
    for (int i = 0; i < 3; ++i) {
        int idx = i * 256 + tid;
        int d = idx >> 2, c = idx & 3;
        bf16x8 v = *reinterpret_cast<const bf16x8*>(wT + (long)d * 1024 + 8 * c);
        *reinterpret_cast<bf16x8*>(&wl[0][d][8 * c]) = v;
    }
    float4 nx0 = *reinterpret_cast<const float4*>(xrow);
    float4 nx1 = *reinterpret_cast<const float4*>(xrow + 4);
    __syncthreads();

    for (int ks = 0; ks < 32; ++ks) {
        const int buf = ks & 1;
        float4 x0 = nx0, x1 = nx1;
        if (ks + 1 < 32) {
            nx0 = *reinterpret_cast<const float4*>(xrow + (ks + 1) * 32);
            nx1 = *reinterpret_cast<const float4*>(xrow + (ks + 1) * 32 + 4);
            #pragma unroll
            for (int i = 0; i < 3; ++i) {
                int idx = i * 256 + tid;
                int d = idx >> 2, c = idx & 3;
                bf16x8 v = *reinterpret_cast<const bf16x8*>(wT + (long)d * 1024 + (ks + 1) * 32 + 8 * c);
                *reinterpret_cast<bf16x8*>(&wl[buf ^ 1][d][8 * c]) = v;
            }
        }
        bf16x8 af = {(bf16_t)x0.x, (bf16_t)x0.y, (bf16_t)x0.z, (bf16_t)x0.w,
                     (bf16_t)x1.x, (bf16_t)x1.y, (bf16_t)x1.z, (bf16_t)x1.w};
        #pragma unroll
        for (int j = 0; j < 6; ++j) {
            const int nt = 6 * nw + j;
            bf16x8 bfr = *reinterpret_cast<const bf16x8*>(&wl[buf][nt * 16 + q4][8 * g]);
            acc[j] = __builtin_amdgcn_mfma_f32_16x16x32_bf16(af, bfr, acc[j], 0, 0, 0);
        }
        __syncthreads();
    }

    // epilogue: nw=0 -> q0..3,k0,k1 ; nw=1 -> k2,k3,v0..3 (v via LDS transpose)
    #pragma unroll
    for (int j = 0; j < 6; ++j) {
        const int nt = 6 * nw + j;
        #pragma unroll
        for (int r = 0; r < 4; ++r) {
            long row = R0 + 16 * mw + 4 * g + r;
            float vv = acc[j][r];
            if (nt < 4)      qh[row * 64 + nt * 16 + q4] = (bf16_t)(vv * 0.125f);
            else if (nt < 8) kh[row * 64 + (nt - 4) * 16 + q4] = (bf16_t)vv;
            else             vtl[(nt - 8) * 16 + q4][16 * mw + 4 * g + r] = vv;
        }
    }
    __syncthreads();
    {
        const int d = tid >> 2, c = tid & 3;
        bf16x8 o;
        #pragma unroll
        for (int i = 0; i < 8; ++i) o[i] = (bf16_t)vtl[d][8 * c + i];
        *reinterpret_cast<bf16x8*>(vt + (long)d * 8192 + R0 + 8 * c) = o;
    }
}

// ---------------------------------------------------------------------------
// attn: flash, block = 64 queries (4 waves Msplit), lockstep chunk walk so
// K/V hit L1 across waves.  Round-robin causal segment split: seg s handles
// chunks s, s+8, ...  Partials (m, l, O/l as f16) -> ws; merged later.
// ---------------------------------------------------------------------------
__global__ __launch_bounds__(256, 4) void attn_mfma(
    const bf16_t* __restrict__ qh, const bf16_t* __restrict__ kh,
    const bf16_t* __restrict__ vt,
    f16_t* __restrict__ pO, float* __restrict__ pm, float* __restrict__ pl)
{
    __shared__ __align__(16) bf16_t P[4][8][16][8];   // per-wave P tiles
    __shared__ float ot[4][16][68];

    const int tid = threadIdx.x, lane = tid & 63, w = tid >> 6;
    const int q4 = lane & 15, g = lane >> 4;
    const int bx = blockIdx.x, b = blockIdx.y;
    const int tile = 63 - (bx >> 3);     // deep tiles first
    const int seg  = bx & 7;
    const int C = tile + 1;              // causal chunk count (64 keys each)
    if (seg >= C) return;
    const long base = (long)b * TSEQ;
    const int r0 = tile * 64 + 16 * w;   // this wave's first query row

    const bf16_t* qr = qh + (base + r0 + q4) * 64 + 8 * g;
    const bf16x8 qf0 = *reinterpret_cast<const bf16x8*>(qr);
    const bf16x8 qf1 = *reinterpret_cast<const bf16x8*>(qr + 32);

    float m = -1e30f, l = 0.f;
    f32x4 oacc[4] = {};

    for (int c = seg; c < C; c += SEGS) {
        const int kb = c << 6;
        // ---- S^T = K-rows x Q
        f32x4 sacc[4];
        #pragma unroll
        for (int kt = 0; kt < 4; ++kt) {
            const bf16_t* kr = kh + (base + kb + kt * 16 + q4) * 64 + 8 * g;
            bf16x8 kf0 = *reinterpret_cast<const bf16x8*>(kr);
            bf16x8 kf1 = *reinterpret_cast<const bf16x8*>(kr + 32);
            f32x4 a = {};
            a = __builtin_amdgcn_mfma_f32_16x16x32_bf16(kf0, qf0, a, 0, 0, 0);
            a = __builtin_amdgcn_mfma_f32_16x16x32_bf16(kf1, qf1, a, 0, 0, 0);
            sacc[kt] = a;
        }
        // ---- online softmax (lane: 16 scores of query q4)
        float p[16];
        const bool diag = (c == C - 1);
        float mx = -1e30f;
        #pragma unroll
        for (int kt = 0; kt < 4; ++kt)
            #pragma unroll
            for (int r = 0; r < 4; ++r) {
                float sv = sacc[kt][r];
                if (diag && (kb + kt * 16 + 4 * g + r > r0 + q4)) sv = -1e30f;
                p[kt * 4 + r] = sv;
                mx = fmaxf(mx, sv);
            }
        mx = fmaxf(mx, __shfl_xor(mx, 16));
        mx = fmaxf(mx, __shfl_xor(mx, 32));
        const float mnew = fmaxf(m, mx);
        const float alpha = __expf(m - mnew);
        m = mnew;
        float lsum = 0.f;
        #pragma unroll
        for (int i = 0; i < 16; ++i) { p[i] = __expf(p[i] - mnew); lsum += p[i]; }
        lsum += __shfl_xor(lsum, 16);
        lsum += __shfl_xor(lsum, 32);
        l = l * alpha + lsum;
        #pragma unroll
        for (int dt = 0; dt < 4; ++dt) oacc[dt] *= alpha;
        // ---- pack P (bf16) into this wave's LDS tile
        #pragma unroll
        for (int kt = 0; kt < 4; ++kt) {
            const int cb = 2 * kt + (g >> 1);
            const int ki = (g & 1) << 2;
            bf16x4 hv = {(bf16_t)p[4*kt+0], (bf16_t)p[4*kt+1],
                         (bf16_t)p[4*kt+2], (bf16_t)p[4*kt+3]};
            *reinterpret_cast<bf16x4*>(&P[w][cb][q4][ki]) = hv;
        }
        // ---- PV: O^T += V^T x P^T
        bf16x8 ph0 = *reinterpret_cast<const bf16x8*>(&P[w][g][q4][0]);
        bf16x8 ph1 = *reinterpret_cast<const bf16x8*>(&P[w][4 + g][q4][0]);
        #pragma unroll
        for (int dt = 0; dt < 4; ++dt) {
            const bf16_t* vr = vt + (long)(dt * 16 + q4) * 8192 + base + kb + 8 * g;
            bf16x8 va0 = *reinterpret_cast<const bf16x8*>(vr);
            bf16x8 va1 = *reinterpret_cast<const bf16x8*>(vr + 32);
            oacc[dt] = __builtin_amdgcn_mfma_f32_16x16x32_bf16(va0, ph0, oacc[dt], 0, 0, 0);
            oacc[dt] = __builtin_amdgcn_mfma_f32_16x16x32_bf16(va1, ph1, oacc[dt], 0, 0, 0);
        }
    }

    // ---- epilogue: normalize, transpose via LDS, store f16 partial
    const float invl = 1.0f / l;
    #pragma unroll
    for (int dt = 0; dt < 4; ++dt)
        #pragma unroll
        for (int r = 0; r < 4; ++r)
            ot[w][q4][dt * 16 + 4 * g + r] = oacc[dt][r] * invl;

    const long pbase = (((long)b * 64 + tile) * SEGS + seg) * 64;
    {
        const int q  = lane >> 2;
        const int dc = (lane & 3) * 16;
        f16x8 o0, o1;
        #pragma unroll
        for (int i = 0; i < 8; ++i) {
            o0[i] = (f16_t)ot[w][q][dc + i];
            o1[i] = (f16_t)ot[w][q][dc + 8 + i];
        }
        f16_t* dst = pO + (pbase + 16 * w + q) * 64 + dc;
        *reinterpret_cast<f16x8*>(dst)     = o0;
        *reinterpret_cast<f16x8*>(dst + 8) = o1;
    }
    if (g == 0) {
        pm[pbase + 16 * w + q4] = m;
        pl[pbase + 16 * w + q4] = l;
    }
}

// ---------------------------------------------------------------------------
// merge: combine active segs per 64q tile -> final O (fp32).
// ---------------------------------------------------------------------------
__global__ __launch_bounds__(256) void merge_k(
    const f16_t* __restrict__ pO, const float* __restrict__ pm,
    const float* __restrict__ pl, float* __restrict__ O)
{
    const int tile = blockIdx.x, b = blockIdx.y;
    const int C = tile + 1;
    const int S = (C < SEGS) ? C : SEGS;
    const int t = threadIdx.x;
    const int q = t >> 2, dc = (t & 3) * 16;
    const long pb = ((long)b * 64 + tile) * SEGS;

    float mstar = -1e30f;
    for (int s = 0; s < S; ++s) mstar = fmaxf(mstar, pm[(pb + s) * 64 + q]);
    float L = 0.f;
    float o[16];
    #pragma unroll
    for (int i = 0; i < 16; ++i) o[i] = 0.f;
    for (int s = 0; s < S; ++s) {
        const float ws = __expf(pm[(pb + s) * 64 + q] - mstar) * pl[(pb + s) * 64 + q];
        L += ws;
        const f16_t* src = pO + ((pb + s) * 64 + q) * 64 + dc;
        f16x8 a0 = *reinterpret_cast<const f16x8*>(src);
        f16x8 a1 = *reinterpret_cast<const f16x8*>(src + 8);
        #pragma unroll
        for (int i = 0; i < 8; ++i) {
            o[i]     += ws * (float)a0[i];
            o[8 + i] += ws * (float)a1[i];
        }
    }
    const float inv = 1.0f / L;
    float* dst = O + ((long)b * TSEQ + tile * 64 + q) * 64 + dc;
    #pragma unroll
    for (int i = 0; i < 4; ++i) {
        f32x4 v = {o[4*i] * inv, o[4*i+1] * inv, o[4*i+2] * inv, o[4*i+3] * inv};
        *reinterpret_cast<f32x4*>(dst + 4 * i) = v;
    }
}

extern "C" void kernel_launch(void* const* d_in, const int* in_sizes, int n_in,
                              void* d_out, int out_size, void* d_ws, size_t ws_size,
                              hipStream_t stream)
{
    const float* X  = (const float*)d_in[0];
    const float* Wq = (const float*)d_in[1];
    const float* Wk = (const float*)d_in[2];
    const float* Wv = (const float*)d_in[3];
    float* O = (float*)d_out;

    char* ws = (char*)d_ws;
    size_t off = 0;
    bf16_t* wT = (bf16_t*)(ws + off); off += 192 * 1024 * sizeof(bf16_t);     // 384 KB
    bf16_t* qh = (bf16_t*)(ws + off); off += 8192L * 64 * sizeof(bf16_t);     // 1 MB
    bf16_t* kh = (bf16_t*)(ws + off); off += 8192L * 64 * sizeof(bf16_t);     // 1 MB
    bf16_t* vt = (bf16_t*)(ws + off); off += 64L * 8192 * sizeof(bf16_t);     // 1 MB
    f16_t*  pO = (f16_t*)(ws + off);  off += 2L * 64 * SEGS * 64 * 64 * sizeof(f16_t); // 8.4 MB
    float*  pm = (float*)(ws + off);  off += 2L * 64 * SEGS * 64 * sizeof(float);
    float*  pl = (float*)(ws + off);  off += 2L * 64 * SEGS * 64 * sizeof(float);

    wsplit_k <<<48, 256, 0, stream>>>(Wq, Wk, Wv, wT);
    proj_mfma<<<256, 256, 0, stream>>>(X, wT, qh, kh, vt);
    attn_mfma<<<dim3(512, 2), 256, 0, stream>>>(qh, kh, vt, pO, pm, pl);
    merge_k  <<<dim3(64, 2), 256, 0, stream>>>(pO, pm, pl, O);
}